// Round 1
// baseline (124.018 us; speedup 1.0000x reference)
//
#include <hip/hip_runtime.h>

// FCOS Revision_PRED refinement.
// Outputs (flat float32, in return order):
//   [0, N2*4)                     refined_boxes [N2,4]
//   [N2*4, N2*5)                  s2            [N2]
//   [N2*5, N2*6)                  c2            [N2] (int -> float)
//   [N2*6, N2*6+N1)               missing_mask  [N1] (bool -> 0/1)
//   [N2*6+N1, ... +N1*N2)         ious          [N1,N2]

constexpr int TOPK = 9;  // up to 8 suppressions + final winner

// ---------------------------------------------------------------------------
// Kernel A: IoU matrix + per-row any(iou>=0.5) flag + per-column partial top-9
// thread = one column; block = 256 columns; blockIdx.y = row split
// ---------------------------------------------------------------------------
__global__ __launch_bounds__(256) void iou_topk_kernel(
    const float* __restrict__ b1, const float* __restrict__ b2,
    float* __restrict__ ious, unsigned int* __restrict__ flags,
    unsigned long long* __restrict__ top,
    int n1, int n2, int rows_per_split, int S)
{
    const int c = blockIdx.x * blockDim.x + threadIdx.x;
    const int s = blockIdx.y;
    if (c >= n2) return;

    const float4 box2 = reinterpret_cast<const float4*>(b2)[c];
    const float a2 = (box2.z - box2.x) * (box2.w - box2.y);

    float tv[TOPK];
    int   ti[TOPK];
#pragma unroll
    for (int j = 0; j < TOPK; ++j) { tv[j] = 0.5f; ti[j] = -1; }

    const int r0 = s * rows_per_split;
    const int r1 = min(r0 + rows_per_split, n1);
    for (int r = r0; r < r1; ++r) {
        const float4 box1 = reinterpret_cast<const float4*>(b1)[r];  // uniform
        const float a1 = (box1.z - box1.x) * (box1.w - box1.y);
        const float ltx = fmaxf(box1.x, box2.x);
        const float lty = fmaxf(box1.y, box2.y);
        const float rbx = fminf(box1.z, box2.z);
        const float rby = fminf(box1.w, box2.w);
        const float wx = fmaxf(rbx - ltx, 0.0f);
        const float wy = fmaxf(rby - lty, 0.0f);
        const float ov = wx * wy;
        const float un = fmaxf(a1 + a2 - ov, 1e-6f);
        const float v = ov / un;                      // IEEE div, matches np
        ious[(size_t)r * n2 + c] = v;

        // per-row "any iou >= 0.5" (missing_mask is suppression-invariant)
        if (__ballot(v >= 0.5f)) {
            if ((threadIdx.x & 63u) == 0u) flags[r] = 1u;
        }

        // top-9 insert, only entries > 0.5 matter; rare branch
        if (v > tv[TOPK - 1]) {
#pragma unroll
            for (int j = TOPK - 1; j >= 0; --j) {
                const bool gt_cur  = v > tv[j];
                const bool gt_prev = (j > 0) ? (v > tv[j - 1]) : false;
                if (gt_cur) {
                    if (gt_prev) { tv[j] = tv[j - 1]; ti[j] = ti[j - 1]; }
                    else         { tv[j] = v;         ti[j] = r; }
                }
            }
        }
    }

    const size_t base = ((size_t)c * S + s) * TOPK;
#pragma unroll
    for (int j = 0; j < TOPK; ++j)
        top[base + j] = ((unsigned long long)__float_as_uint(tv[j]) << 32)
                      | (unsigned long long)(unsigned int)ti[j];
}

// ---------------------------------------------------------------------------
// Kernel B: merge partial top-9 lists, simulate <=8 suppressions, write
// refined boxes/scores/classes and scatter the 0.5 suppressions into ious.
// ---------------------------------------------------------------------------
__global__ __launch_bounds__(256) void refine_kernel(
    const float* __restrict__ b1, const float* __restrict__ s1,
    const int* __restrict__ c1,
    const float* __restrict__ b2, const float* __restrict__ s2,
    const int* __restrict__ c2,
    const unsigned long long* __restrict__ top,
    float* __restrict__ out_boxes, float* __restrict__ out_s,
    float* __restrict__ out_c, float* __restrict__ ious,
    int n2, int S)
{
    const int c = blockIdx.x * blockDim.x + threadIdx.x;
    if (c >= n2) return;

    float tv[TOPK];
    int   ti[TOPK];
#pragma unroll
    for (int j = 0; j < TOPK; ++j) { tv[j] = 0.5f; ti[j] = -1; }

    // splits processed in ascending row order => indices ascend; strict '>'
    // insertion preserves jnp.argmax first-index tie-breaking.
    for (int s = 0; s < S; ++s) {
        const size_t base = ((size_t)c * S + s) * TOPK;
        for (int e = 0; e < TOPK; ++e) {
            const unsigned long long pk = top[base + e];
            const float v = __uint_as_float((unsigned int)(pk >> 32));
            if (!(v > 0.5f)) break;   // lists are sorted desc; rest are sentinels
            const int r = (int)(unsigned int)(pk & 0xffffffffull);
#pragma unroll
            for (int j = TOPK - 1; j >= 0; --j) {
                const bool gt_cur  = v > tv[j];
                const bool gt_prev = (j > 0) ? (v > tv[j - 1]) : false;
                if (gt_cur) {
                    if (gt_prev) { tv[j] = tv[j - 1]; ti[j] = ti[j - 1]; }
                    else         { tv[j] = v;         ti[j] = r; }
                }
            }
        }
    }

    int cnt = 0;
#pragma unroll
    for (int j = 0; j < TOPK; ++j) cnt += (tv[j] > 0.5f) ? 1 : 0;

    const float s2c = s2[c];
    float s1v[TOPK];
#pragma unroll
    for (int j = 0; j < TOPK; ++j) s1v[j] = (j < cnt) ? s1[ti[j]] : 0.0f;

    // k = length of maximal prefix with scores1 < scores2 (suppressed), cap 8
    int k = 0;
#pragma unroll
    for (int j = 0; j < 8; ++j)
        if (j < cnt && k == j && s1v[j] < s2c) k = j + 1;

    // scatter the suppressions (entries replaced by exactly 0.5)
#pragma unroll
    for (int j = 0; j < 8; ++j)
        if (j < k) ious[(size_t)ti[j] * n2 + c] = 0.5f;

    const bool refine = (k < cnt);
    int winner = -1; float wscore = 0.0f;
#pragma unroll
    for (int j = 0; j < TOPK; ++j)
        if (j == k) { winner = ti[j]; wscore = s1v[j]; }

    float4 ob; float os, oc;
    if (refine) {
        ob = reinterpret_cast<const float4*>(b1)[winner];
        os = wscore;
        oc = (float)c1[winner];
    } else {
        ob = reinterpret_cast<const float4*>(b2)[c];
        os = s2c;
        oc = (float)c2[c];
    }
    // (b + |b|) * 0.5 == max(b, 0)
    ob.x = fmaxf(ob.x, 0.0f); ob.y = fmaxf(ob.y, 0.0f);
    ob.z = fmaxf(ob.z, 0.0f); ob.w = fmaxf(ob.w, 0.0f);
    reinterpret_cast<float4*>(out_boxes)[c] = ob;
    out_s[c] = os;
    out_c[c] = oc;
}

// ---------------------------------------------------------------------------
// Kernel C: missing_mask[r] = !any(iou >= 0.5) as 0/1 float
// ---------------------------------------------------------------------------
__global__ void missing_kernel(const unsigned int* __restrict__ flags,
                               float* __restrict__ out_m, int n1)
{
    const int r = blockIdx.x * blockDim.x + threadIdx.x;
    if (r < n1) out_m[r] = flags[r] ? 0.0f : 1.0f;
}

extern "C" void kernel_launch(void* const* d_in, const int* in_sizes, int n_in,
                              void* d_out, int out_size, void* d_ws, size_t ws_size,
                              hipStream_t stream) {
    (void)n_in; (void)out_size;
    const float* b1 = (const float*)d_in[0];
    const float* s1 = (const float*)d_in[1];
    const int*   c1 = (const int*)d_in[2];
    const float* b2 = (const float*)d_in[3];
    const float* s2 = (const float*)d_in[4];
    const int*   c2 = (const int*)d_in[5];
    const int n1 = in_sizes[1];   // scores1 count = 8192
    const int n2 = in_sizes[4];   // scores2 count = 4096

    float* out       = (float*)d_out;
    float* out_boxes = out;
    float* out_s     = out + (size_t)n2 * 4;
    float* out_c     = out_s + n2;
    float* out_m     = out_c + n2;
    float* out_ious  = out_m + n1;

    // ws: [flags: n1 u32][top: n2 * S * TOPK u64]
    const size_t flag_bytes = (size_t)n1 * sizeof(unsigned int);
    int S = 32;
    while (S > 1 && flag_bytes + (size_t)n2 * S * TOPK * 8 > ws_size) S >>= 1;
    unsigned int* flags = (unsigned int*)d_ws;
    unsigned long long* top = (unsigned long long*)((char*)d_ws + flag_bytes);

    hipMemsetAsync(d_ws, 0, flag_bytes, stream);

    const int rows_per_split = (n1 + S - 1) / S;
    dim3 gridA((n2 + 255) / 256, S);
    iou_topk_kernel<<<gridA, 256, 0, stream>>>(b1, b2, out_ious, flags, top,
                                               n1, n2, rows_per_split, S);
    refine_kernel<<<(n2 + 255) / 256, 256, 0, stream>>>(
        b1, s1, c1, b2, s2, c2, top, out_boxes, out_s, out_c, out_ious, n2, S);
    missing_kernel<<<(n1 + 255) / 256, 256, 0, stream>>>(flags, out_m, n1);
}